// Round 12
// baseline (125.734 us; speedup 1.0000x reference)
//
#include <hip/hip_runtime.h>
#include <limits.h>
#include <stdint.h>

#define ALPHA 0.2f
#define HALFA 0.1f
static constexpr int N = 8192;
static constexpr int D = 128;
static constexpr int C = 512;
static constexpr int BT = 128;          // block tile (i and j)
static constexpr int KC = 32;           // k-chunk in fp16 elems (R4-proven)
static constexpr int SL = 40;           // LDS row stride in fp16 (32 + 8 pad, R4-proven)
static constexpr int NB = N / BT;       // 64
static constexpr int NTRI = NB * (NB + 1) / 2;   // 2080 triangle blocks
static constexpr int NTAB = (C / BT) * NB;       // 256 anchor-Gram (term1) blocks
static constexpr int CAP = 48;          // e-list capacity per label (Poisson(16): P(>=48) ~ 1e-11)
static constexpr int ABIAS = 0x40000000; // anchor: atomicMax(ABIAS - i); 0xAA poison < all

using half8   = __attribute__((ext_vector_type(8))) _Float16;
using half2v  = __attribute__((ext_vector_type(2))) _Float16;
using floatx16 = __attribute__((ext_vector_type(16))) float;

__device__ __forceinline__ floatx16 zerov() { floatx16 v = {0.f}; return v; }

// ---------------- prep: fp16 convert + sq + anchor + zero out ----------------

__global__ void k_prep(const float* __restrict__ x, const int* __restrict__ labels,
                       _Float16* __restrict__ xh, float* __restrict__ sq,
                       int* __restrict__ anchor, float* __restrict__ out) {
    int row = (blockIdx.x * blockDim.x + threadIdx.x) >> 6;
    int lane = threadIdx.x & 63;
    float2 v = ((const float2*)(x + (size_t)row * D))[lane];
    half2v h; h[0] = (_Float16)v.x; h[1] = (_Float16)v.y;
    *(half2v*)(xh + (size_t)row * D + lane * 2) = h;
    float s = v.x * v.x + v.y * v.y;
#pragma unroll
    for (int off = 32; off; off >>= 1) s += __shfl_down(s, off);
    if (lane == 0) {
        sq[row] = s;
        atomicMax(&anchor[labels[row]], ABIAS - row);   // min-index via max-encode
    }
    if (blockIdx.x == 0 && threadIdx.x == 0) out[0] = 0.f;
}

// ---------------- ap: one wave per row, fp32 exact dot with anchor row ----------------

__global__ void k_ap(const float* __restrict__ x, const int* __restrict__ labels,
                     const int* __restrict__ anchor, const float* __restrict__ sq,
                     float* __restrict__ ap) {
    int i = (blockIdx.x * blockDim.x + threadIdx.x) >> 6;
    int lane = threadIdx.x & 63;
    int a = ABIAS - anchor[labels[i]];
    float2 vi = ((const float2*)(x + (size_t)i * D))[lane];
    float2 va = ((const float2*)(x + (size_t)a * D))[lane];
    float dp = vi.x * va.x + vi.y * va.y;
#pragma unroll
    for (int off = 32; off; off >>= 1) dp += __shfl_down(dp, off);
    if (lane == 0) ap[i] = sq[a] + sq[i] - 2.0f * dp;
}

// ---------------- mega: anchor-Gram term1 blocks + triangle term2 blocks ----------------
// shared-memory plan (byte offsets into smem):
//   [0,10240)      As tile
//   [10240,20480)  Bs tile
//   family T1: [20480,45056) elist[128][CAP] | [45056,45568) lcnt | [45568,46080) sSqA
//              [46080,46592) sAnc | [46592,47616) colJ(float2)
//   family T2: [20480,22528) rowE(float4) | [22528,24576) colE(float4)

__launch_bounds__(256)
__global__ void k_mega(const _Float16* __restrict__ xh, const int* __restrict__ labels,
                       const int* __restrict__ anchor, const float* __restrict__ sq,
                       const float* __restrict__ ap, float* __restrict__ out) {
    __shared__ __align__(16) char smem[47616];
    __shared__ float wsum[4];

    _Float16* As = (_Float16*)smem;
    _Float16* Bs = (_Float16*)(smem + 10240);

    const int tid = threadIdx.x;
    const int lane = tid & 63, w = tid >> 6;
    const int wr = w >> 1, wc = w & 1;
    const int m = lane & 31, q = lane >> 5;
    float local = 0.f;

    if ((int)blockIdx.x < NTAB) {
        // ---- term1: anchor-Gram tile (c0..c0+128) x (j0..j0+128), hinge vs LDS e-lists ----
        float* elist = (float*)(smem + 20480);
        int*   lcnt  = (int*)(smem + 45056);
        float* sSqA  = (float*)(smem + 45568);
        int*   sAnc  = (int*)(smem + 46080);
        float2* colJ = (float2*)(smem + 46592);

        const int c0 = ((int)blockIdx.x & 3) * BT;
        const int j0 = ((int)blockIdx.x >> 2) * BT;

        if (tid < BT) {
            lcnt[tid] = 0;
            int c = c0 + tid;
            int raw = anchor[c];
            int a = (raw > 0) ? (ABIAS - raw) : -1;   // -1: label absent
            sAnc[tid] = a;
            sSqA[tid] = sq[a < 0 ? 0 : a];
        } else {
            int t = tid - BT;
            int j = j0 + t;
            colJ[t] = make_float2(sq[j], __int_as_float(labels[j]));
        }
        __syncthreads();

        // gather e-lists: scan all labels, collect non-anchor members of c-range
        const int4* lab4 = (const int4*)labels;
        for (int t = tid; t < N / 4; t += 256) {
            int4 lv = lab4[t];
            int mbase = t * 4;
#pragma unroll
            for (int k = 0; k < 4; ++k) {
                int l = (k == 0) ? lv.x : (k == 1) ? lv.y : (k == 2) ? lv.z : lv.w;
                int li = l - c0;
                if ((unsigned)li < (unsigned)BT) {
                    int mm = mbase + k;
                    if (mm != sAnc[li]) {
                        int slot = atomicAdd(&lcnt[li], 1);
                        if (slot < CAP) elist[li * CAP + slot] = ap[mm] + HALFA;
                    }
                }
            }
        }

        floatx16 acc[2][2];
        acc[0][0] = zerov(); acc[0][1] = zerov(); acc[1][0] = zerov(); acc[1][1] = zerov();

        const _Float16* Abase = &As[(wr * 64 + m) * SL + q * 8];
        const _Float16* Bbase = &Bs[(wc * 64 + m) * SL + q * 8];

        for (int kc = 0; kc < D; kc += KC) {
            __syncthreads();
#pragma unroll
            for (int it = 0; it < 2; ++it) {
                int f = tid + it * 256;
                int row = f >> 2, g = f & 3;
                size_t go = (size_t)kc + g * 8;
                int ar = sAnc[row]; if (ar < 0) ar = 0;
                half8 v = *(const half8*)(xh + (size_t)ar * D + go);
                *(half8*)(&As[row * SL + g * 8]) = v;
                half8 u = *(const half8*)(xh + (size_t)(j0 + row) * D + go);
                *(half8*)(&Bs[row * SL + g * 8]) = u;
            }
            __syncthreads();
#pragma unroll
            for (int ks = 0; ks < KC; ks += 16) {
                half8 a0 = *(const half8*)(Abase + ks);
                half8 a1 = *(const half8*)(Abase + 32 * SL + ks);
                half8 b0 = *(const half8*)(Bbase + ks);
                half8 b1 = *(const half8*)(Bbase + 32 * SL + ks);
                acc[0][0] = __builtin_amdgcn_mfma_f32_32x32x16_f16(a0, b0, acc[0][0], 0, 0, 0);
                acc[0][1] = __builtin_amdgcn_mfma_f32_32x32x16_f16(a0, b1, acc[0][1], 0, 0, 0);
                acc[1][0] = __builtin_amdgcn_mfma_f32_32x32x16_f16(a1, b0, acc[1][0], 0, 0, 0);
                acc[1][1] = __builtin_amdgcn_mfma_f32_32x32x16_f16(a1, b1, acc[1][1], 0, 0, 0);
            }
        }

        float sqj[2]; int labj[2];
#pragma unroll
        for (int tn = 0; tn < 2; ++tn) {
            float2 cj = colJ[wc * 64 + tn * 32 + m];
            sqj[tn] = cj.x; labj[tn] = __float_as_int(cj.y);
        }

        // per element (c,j): Dv = sq_a + sq_j - 2*dot; for e in list[c]:
        // u = e - Dv contributes (u + a/2) iff |u| < a/2, j a negative (lab_j != c)
#pragma unroll
        for (int tm = 0; tm < 2; ++tm) {
            int rbase = wr * 64 + tm * 32 + 4 * q;
#pragma unroll
            for (int rr = 0; rr < 16; ++rr) {
                int row = rbase + (rr & 3) + 8 * (rr >> 2);
                int c = c0 + row;
                int glen = lcnt[row]; if (glen > CAP) glen = CAP;
                if (glen == 0) continue;
                float sqa = sSqA[row];
                const float* el = &elist[row * CAP];
#pragma unroll
                for (int tn = 0; tn < 2; ++tn) {
                    if (labj[tn] == c) continue;
                    float Dv = fmaf(-2.f, acc[tm][tn][rr], sqa + sqj[tn]);
                    for (int g = 0; g < glen; ++g) {
                        float u = el[g] - Dv;
                        if (__builtin_fabsf(u) < HALFA) local += u + HALFA;
                    }
                }
            }
        }
    } else {
        // ---- term2: symmetric Gram triangle, register-only epilogue (R11-proven) ----
        float4* rowE = (float4*)(smem + 20480);
        float4* colE = (float4*)(smem + 22528);

        int rem = blockIdx.x - NTAB, br = 0;
        while (rem >= NB - br) { rem -= NB - br; ++br; }
        const int bc = br + rem;
        const int i0 = br * BT;
        const int j0 = bc * BT;
        const bool diag = (br == bc);

        if (tid < BT) {
            int i = i0 + tid;
            int li = labels[i];
            int a = ABIAS - anchor[li];
            float sqi = sq[i];
            float e2 = (i == a) ? -1e30f : ap[i] + HALFA - sqi;
            rowE[tid] = make_float4(e2, __int_as_float(li), sqi, 0.f);
        } else {
            int t = tid - BT;
            int j = j0 + t;
            int lj = labels[j];
            int a = ABIAS - anchor[lj];
            float sqj = sq[j];
            float e2 = (j == a) ? -1e30f : ap[j] + HALFA - sqj;
            colE[t] = make_float4(e2, __int_as_float(lj), sqj, 0.f);
        }

        floatx16 acc[2][2];
        acc[0][0] = zerov(); acc[0][1] = zerov(); acc[1][0] = zerov(); acc[1][1] = zerov();

        const _Float16* Abase = &As[(wr * 64 + m) * SL + q * 8];
        const _Float16* Bbase = &Bs[(wc * 64 + m) * SL + q * 8];

        for (int kc = 0; kc < D; kc += KC) {
            __syncthreads();
#pragma unroll
            for (int it = 0; it < 2; ++it) {
                int f = tid + it * 256;
                int row = f >> 2, g = f & 3;
                size_t go = (size_t)kc + g * 8;
                half8 v = *(const half8*)(xh + (size_t)(i0 + row) * D + go);
                *(half8*)(&As[row * SL + g * 8]) = v;
                half8 u = *(const half8*)(xh + (size_t)(j0 + row) * D + go);
                *(half8*)(&Bs[row * SL + g * 8]) = u;
            }
            __syncthreads();
#pragma unroll
            for (int ks = 0; ks < KC; ks += 16) {
                half8 a0 = *(const half8*)(Abase + ks);
                half8 a1 = *(const half8*)(Abase + 32 * SL + ks);
                half8 b0 = *(const half8*)(Bbase + ks);
                half8 b1 = *(const half8*)(Bbase + 32 * SL + ks);
                acc[0][0] = __builtin_amdgcn_mfma_f32_32x32x16_f16(a0, b0, acc[0][0], 0, 0, 0);
                acc[0][1] = __builtin_amdgcn_mfma_f32_32x32x16_f16(a0, b1, acc[0][1], 0, 0, 0);
                acc[1][0] = __builtin_amdgcn_mfma_f32_32x32x16_f16(a1, b0, acc[1][0], 0, 0, 0);
                acc[1][1] = __builtin_amdgcn_mfma_f32_32x32x16_f16(a1, b1, acc[1][1], 0, 0, 0);
            }
        }

        float sqj[2], e2j[2]; int labj[2];
#pragma unroll
        for (int tn = 0; tn < 2; ++tn) {
            float4 cj = colE[wc * 64 + tn * 32 + m];
            e2j[tn] = cj.x; labj[tn] = __float_as_int(cj.y); sqj[tn] = cj.z;
        }

        // ori1 (i pos): u2 = 2*dot + e2i - sq_j ; ori2 (j pos): u2b = 2*dot + e2j - sq_i
#pragma unroll
        for (int tm = 0; tm < 2; ++tm) {
            int rbase = wr * 64 + tm * 32 + 4 * q;
#pragma unroll
            for (int rr = 0; rr < 16; ++rr) {
                int row = rbase + (rr & 3) + 8 * (rr >> 2);
                float4 re = rowE[row];
                float e2i = re.x, sqi = re.z;
                int labi = __float_as_int(re.y);
#pragma unroll
                for (int tn = 0; tn < 2; ++tn) {
                    if (labi != labj[tn]) {
                        float dot = acc[tm][tn][rr];
                        float u2 = fmaf(2.f, dot, e2i - sqj[tn]);
                        if (__builtin_fabsf(u2) < HALFA) local += u2 + HALFA;
                        if (!diag) {
                            float u2b = fmaf(2.f, dot, e2j[tn] - sqi);
                            if (__builtin_fabsf(u2b) < HALFA) local += u2b + HALFA;
                        }
                    }
                }
            }
        }
    }

    // block reduce -> one fire-and-forget float atomic
#pragma unroll
    for (int off = 32; off; off >>= 1) local += __shfl_down(local, off);
    if (lane == 0) wsum[w] = local;
    __syncthreads();
    if (tid == 0) atomicAdd(out, wsum[0] + wsum[1] + wsum[2] + wsum[3]);
}

// ---------------- launch ----------------

extern "C" void kernel_launch(void* const* d_in, const int* in_sizes, int n_in,
                              void* d_out, int out_size, void* d_ws, size_t ws_size,
                              hipStream_t stream) {
    const float* x = (const float*)d_in[0];
    const int* labels = (const int*)d_in[1];
    float* out = (float*)d_out;

    char* p = (char*)d_ws;
    int* anchor = (int*)p;            p += C * 4;
    float* sq = (float*)p;            p += N * 4;
    float* ap = (float*)p;            p += N * 4;
    p = (char*)(((uintptr_t)p + 255) & ~(uintptr_t)255);
    _Float16* xh = (_Float16*)p;      // N*D*2 = 2 MB

    k_prep<<<N / 4, 256, 0, stream>>>(x, labels, xh, sq, anchor, out);
    k_ap<<<N / 4, 256, 0, stream>>>(x, labels, anchor, sq, ap);
    k_mega<<<NTAB + NTRI, 256, 0, stream>>>(xh, labels, anchor, sq, ap, out);
}

// Round 14
// 122.251 us; speedup vs baseline: 1.0285x; 1.0285x over previous
//
#include <hip/hip_runtime.h>
#include <limits.h>
#include <stdint.h>

#define ALPHA 0.2f
#define HALFA 0.1f
static constexpr int N = 8192;
static constexpr int D = 128;
static constexpr int C = 512;
static constexpr int BT = 128;          // block tile (i and j)
static constexpr int KC = 32;           // k-chunk in fp16 elems (R4-proven)
static constexpr int SL = 40;           // LDS row stride in fp16 (32 + 8 pad, R4-proven)
static constexpr int NB = N / BT;       // 64
static constexpr int NTRI = NB * (NB + 1) / 2;   // 2080 triangle blocks
static constexpr int MAXG = 64;         // max group size staged (Poisson(16); >8 sigma)
static constexpr int ABIAS = 0x40000000; // anchor: atomicMax(ABIAS - i); 0xAA poison < all
static constexpr unsigned POIS = 0xAAAAAAAAu; // ws poison pattern (re-applied every launch)

using half8   = __attribute__((ext_vector_type(8))) _Float16;
using half2v  = __attribute__((ext_vector_type(2))) _Float16;
using floatx16 = __attribute__((ext_vector_type(16))) float;

__device__ __forceinline__ floatx16 zerov() { floatx16 v = {0.f}; return v; }

// ---------------- prep: fp16 convert + sq + anchor + group slots (poison-based, no memset) ----

__global__ void k_prep(const float* __restrict__ x, const int* __restrict__ labels,
                       _Float16* __restrict__ xh, float* __restrict__ sq,
                       int* __restrict__ anchor, unsigned* __restrict__ cnt,
                       int* __restrict__ members, float* __restrict__ out) {
    int row = (blockIdx.x * blockDim.x + threadIdx.x) >> 6;
    int lane = threadIdx.x & 63;
    float2 v = ((const float2*)(x + (size_t)row * D))[lane];
    half2v h; h[0] = (_Float16)v.x; h[1] = (_Float16)v.y;
    *(half2v*)(xh + (size_t)row * D + lane * 2) = h;
    float s = v.x * v.x + v.y * v.y;
#pragma unroll
    for (int off = 32; off; off >>= 1) s += __shfl_down(s, off);
    if (lane == 0) {
        sq[row] = s;
        int c = labels[row];
        atomicMax(&anchor[c], ABIAS - row);           // min-index via max-encode on poison
        unsigned slot = atomicAdd(&cnt[c], 1u) - POIS; // cnt starts at poison pattern
        if (slot < (unsigned)MAXG) members[c * MAXG + slot] = row;
    }
    if (blockIdx.x == 0 && threadIdx.x == 0) out[0] = 0.f;
}

// ---------------- table: T[c][j] = D(anchor_c, x_j); ap[j] = T[lab_j][j] ----------------

__launch_bounds__(256)
__global__ void k_table(const _Float16* __restrict__ xh, const int* __restrict__ labels,
                        const int* __restrict__ anchor, const float* __restrict__ sq,
                        float* __restrict__ T, float* __restrict__ ap) {
    __shared__ __align__(16) _Float16 As[BT * SL];   // anchor rows c0..
    __shared__ __align__(16) _Float16 Bs[BT * SL];   // rows j0..
    __shared__ float sSqA[BT];
    __shared__ float2 colJ[BT];    // (sq_j, lab_j bits)
    __shared__ int sAnc[BT];

    const int c0 = blockIdx.x * BT;
    const int j0 = blockIdx.y * BT;
    const int tid = threadIdx.x;
    const int lane = tid & 63, w = tid >> 6;
    const int wr = w >> 1, wc = w & 1;
    const int m = lane & 31, q = lane >> 5;

    if (tid < BT) {
        int c = c0 + tid;
        int raw = anchor[c];
        int a = (raw > 0) ? (ABIAS - raw) : 0;   // empty label -> dummy row (never read)
        sAnc[tid] = a;
        sSqA[tid] = sq[a];
    } else {
        int t = tid - BT;
        int j = j0 + t;
        colJ[t] = make_float2(sq[j], __int_as_float(labels[j]));
    }

    floatx16 acc[2][2];
    acc[0][0] = zerov(); acc[0][1] = zerov(); acc[1][0] = zerov(); acc[1][1] = zerov();

    const _Float16* Abase = &As[(wr * 64 + m) * SL + q * 8];
    const _Float16* Bbase = &Bs[(wc * 64 + m) * SL + q * 8];

    for (int kc = 0; kc < D; kc += KC) {
        __syncthreads();
#pragma unroll
        for (int it = 0; it < 2; ++it) {
            int f = tid + it * 256;
            int row = f >> 2, g = f & 3;
            size_t go = (size_t)kc + g * 8;
            half8 v = *(const half8*)(xh + (size_t)sAnc[row] * D + go);
            *(half8*)(&As[row * SL + g * 8]) = v;
            half8 u = *(const half8*)(xh + (size_t)(j0 + row) * D + go);
            *(half8*)(&Bs[row * SL + g * 8]) = u;
        }
        __syncthreads();
#pragma unroll
        for (int ks = 0; ks < KC; ks += 16) {
            half8 a0 = *(const half8*)(Abase + ks);
            half8 a1 = *(const half8*)(Abase + 32 * SL + ks);
            half8 b0 = *(const half8*)(Bbase + ks);
            half8 b1 = *(const half8*)(Bbase + 32 * SL + ks);
            acc[0][0] = __builtin_amdgcn_mfma_f32_32x32x16_f16(a0, b0, acc[0][0], 0, 0, 0);
            acc[0][1] = __builtin_amdgcn_mfma_f32_32x32x16_f16(a0, b1, acc[0][1], 0, 0, 0);
            acc[1][0] = __builtin_amdgcn_mfma_f32_32x32x16_f16(a1, b0, acc[1][0], 0, 0, 0);
            acc[1][1] = __builtin_amdgcn_mfma_f32_32x32x16_f16(a1, b1, acc[1][1], 0, 0, 0);
        }
    }

    float sqj[2]; int labj[2];
#pragma unroll
    for (int tn = 0; tn < 2; ++tn) {
        float2 cj = colJ[wc * 64 + tn * 32 + m];
        sqj[tn] = cj.x; labj[tn] = __float_as_int(cj.y);
    }

#pragma unroll
    for (int tm = 0; tm < 2; ++tm) {
        int rbase = wr * 64 + tm * 32 + 4 * q;
#pragma unroll
        for (int rr = 0; rr < 16; ++rr) {
            int row = rbase + (rr & 3) + 8 * (rr >> 2);
            int c = c0 + row;
            float sqa = sSqA[row];
#pragma unroll
            for (int tn = 0; tn < 2; ++tn) {
                int col = wc * 64 + tn * 32 + m;
                float Dv = fmaf(-2.f, acc[tm][tn][rr], sqa + sqj[tn]);
                T[(size_t)c * N + j0 + col] = Dv;
                if (labj[tn] == c) ap[j0 + col] = Dv;
            }
        }
    }
}

// ---------------- mega: per-label term1 blocks + term2 triangle blocks ----------------

__launch_bounds__(256)
__global__ void k_mega(const _Float16* __restrict__ xh, const int* __restrict__ labels,
                       const int* __restrict__ anchor, const float* __restrict__ sq,
                       const float* __restrict__ ap, const unsigned* __restrict__ cnt,
                       const int* __restrict__ members, const float* __restrict__ T,
                       float* __restrict__ out) {
    __shared__ __align__(16) _Float16 As[BT * SL];
    __shared__ __align__(16) _Float16 Bs[BT * SL];
    __shared__ float4 rowE[BT];    // (e2i, labi bits, sq_i, -)
    __shared__ float4 colE[BT];    // (e2j, labj bits, sq_j, -)
    __shared__ float wsum[4];

    const int tid = threadIdx.x;
    const int lane = tid & 63, w = tid >> 6;
    float local = 0.f;

    if ((int)blockIdx.x < C) {
        // ---- term1, label c: stream T[c][:] once, hinge against the group e-list ----
        const int c = blockIdx.x;
        __shared__ float sge[MAXG];
        __shared__ int sglen;
        int raw = anchor[c];
        int gc = (int)(cnt[c] - POIS);
        if (raw > 0 && gc >= 2) {
            int a = ABIAS - raw;
            if (tid == 0) sglen = 0;
            __syncthreads();
            if (gc > MAXG) gc = MAXG;
            if (tid < gc) {
                int mm = members[c * MAXG + tid];
                if (mm != a) {
                    int slot = atomicAdd(&sglen, 1);
                    sge[slot] = ap[mm] + HALFA;
                }
            }
            __syncthreads();
            const int glen = sglen;
            const float4* trow = (const float4*)(T + (size_t)c * N);
            const int4* lrow = (const int4*)labels;
#pragma unroll 2
            for (int ch = 0; ch < 8; ++ch) {
                float4 tv = trow[ch * 256 + tid];
                int4 lv = lrow[ch * 256 + tid];
                for (int g = 0; g < glen; ++g) {
                    float e = sge[g];
                    float u;
                    u = e - tv.x; if (lv.x != c && __builtin_fabsf(u) < HALFA) local += u + HALFA;
                    u = e - tv.y; if (lv.y != c && __builtin_fabsf(u) < HALFA) local += u + HALFA;
                    u = e - tv.z; if (lv.z != c && __builtin_fabsf(u) < HALFA) local += u + HALFA;
                    u = e - tv.w; if (lv.w != c && __builtin_fabsf(u) < HALFA) local += u + HALFA;
                }
            }
        }
    } else {
        // ---- term2: symmetric Gram triangle, register-only epilogue ----
        int rem = blockIdx.x - C, br = 0;
        while (rem >= NB - br) { rem -= NB - br; ++br; }
        const int bc = br + rem;
        const int i0 = br * BT;
        const int j0 = bc * BT;
        const bool diag = (br == bc);
        const int wr = w >> 1, wc = w & 1;
        const int m = lane & 31, q = lane >> 5;

        if (tid < BT) {
            int i = i0 + tid;
            int li = labels[i];
            int a = ABIAS - anchor[li];
            float sqi = sq[i];
            float e2 = (i == a) ? -1e30f : ap[i] + HALFA - sqi;
            rowE[tid] = make_float4(e2, __int_as_float(li), sqi, 0.f);
        } else {
            int t = tid - BT;
            int j = j0 + t;
            int lj = labels[j];
            int a = ABIAS - anchor[lj];
            float sqj = sq[j];
            float e2 = (j == a) ? -1e30f : ap[j] + HALFA - sqj;
            colE[t] = make_float4(e2, __int_as_float(lj), sqj, 0.f);
        }

        floatx16 acc[2][2];
        acc[0][0] = zerov(); acc[0][1] = zerov(); acc[1][0] = zerov(); acc[1][1] = zerov();

        const _Float16* Abase = &As[(wr * 64 + m) * SL + q * 8];
        const _Float16* Bbase = &Bs[(wc * 64 + m) * SL + q * 8];

        for (int kc = 0; kc < D; kc += KC) {
            __syncthreads();
#pragma unroll
            for (int it = 0; it < 2; ++it) {
                int f = tid + it * 256;
                int row = f >> 2, g = f & 3;
                size_t go = (size_t)kc + g * 8;
                half8 v = *(const half8*)(xh + (size_t)(i0 + row) * D + go);
                *(half8*)(&As[row * SL + g * 8]) = v;
                half8 u = *(const half8*)(xh + (size_t)(j0 + row) * D + go);
                *(half8*)(&Bs[row * SL + g * 8]) = u;
            }
            __syncthreads();
#pragma unroll
            for (int ks = 0; ks < KC; ks += 16) {
                half8 a0 = *(const half8*)(Abase + ks);
                half8 a1 = *(const half8*)(Abase + 32 * SL + ks);
                half8 b0 = *(const half8*)(Bbase + ks);
                half8 b1 = *(const half8*)(Bbase + 32 * SL + ks);
                acc[0][0] = __builtin_amdgcn_mfma_f32_32x32x16_f16(a0, b0, acc[0][0], 0, 0, 0);
                acc[0][1] = __builtin_amdgcn_mfma_f32_32x32x16_f16(a0, b1, acc[0][1], 0, 0, 0);
                acc[1][0] = __builtin_amdgcn_mfma_f32_32x32x16_f16(a1, b0, acc[1][0], 0, 0, 0);
                acc[1][1] = __builtin_amdgcn_mfma_f32_32x32x16_f16(a1, b1, acc[1][1], 0, 0, 0);
            }
        }

        float sqj[2], e2j[2]; int labj[2];
#pragma unroll
        for (int tn = 0; tn < 2; ++tn) {
            float4 cj = colE[wc * 64 + tn * 32 + m];
            e2j[tn] = cj.x; labj[tn] = __float_as_int(cj.y); sqj[tn] = cj.z;
        }

        // ori1 (i pos): u2 = 2*dot + e2i - sq_j ; ori2 (j pos): u2b = 2*dot + e2j - sq_i
#pragma unroll
        for (int tm = 0; tm < 2; ++tm) {
            int rbase = wr * 64 + tm * 32 + 4 * q;
#pragma unroll
            for (int rr = 0; rr < 16; ++rr) {
                int row = rbase + (rr & 3) + 8 * (rr >> 2);
                float4 re = rowE[row];
                float e2i = re.x, sqi = re.z;
                int labi = __float_as_int(re.y);
#pragma unroll
                for (int tn = 0; tn < 2; ++tn) {
                    if (labi != labj[tn]) {
                        float dot = acc[tm][tn][rr];
                        float u2 = fmaf(2.f, dot, e2i - sqj[tn]);
                        if (__builtin_fabsf(u2) < HALFA) local += u2 + HALFA;
                        if (!diag) {
                            float u2b = fmaf(2.f, dot, e2j[tn] - sqi);
                            if (__builtin_fabsf(u2b) < HALFA) local += u2b + HALFA;
                        }
                    }
                }
            }
        }
    }

    // block reduce -> one fire-and-forget float atomic
#pragma unroll
    for (int off = 32; off; off >>= 1) local += __shfl_down(local, off);
    if (lane == 0) wsum[w] = local;
    __syncthreads();
    if (tid == 0) atomicAdd(out, wsum[0] + wsum[1] + wsum[2] + wsum[3]);
}

// ---------------- launch ----------------

extern "C" void kernel_launch(void* const* d_in, const int* in_sizes, int n_in,
                              void* d_out, int out_size, void* d_ws, size_t ws_size,
                              hipStream_t stream) {
    const float* x = (const float*)d_in[0];
    const int* labels = (const int*)d_in[1];
    float* out = (float*)d_out;

    char* p = (char*)d_ws;
    int* anchor = (int*)p;            p += C * 4;
    unsigned* cnt = (unsigned*)p;     p += C * 4;
    int* members = (int*)p;           p += C * MAXG * 4;   // 128 KB
    float* sq = (float*)p;            p += N * 4;
    float* ap = (float*)p;            p += N * 4;
    p = (char*)(((uintptr_t)p + 255) & ~(uintptr_t)255);
    float* T = (float*)p;             p += (size_t)C * N * 4;   // 16 MB
    _Float16* xh = (_Float16*)p;      // N*D*2 = 2 MB

    k_prep<<<N / 4, 256, 0, stream>>>(x, labels, xh, sq, anchor, cnt, members, out);
    dim3 gt(C / BT, N / BT);
    k_table<<<gt, 256, 0, stream>>>(xh, labels, anchor, sq, T, ap);
    k_mega<<<C + NTRI, 256, 0, stream>>>(xh, labels, anchor, sq, ap, cnt, members, T, out);
}

// Round 15
// 119.187 us; speedup vs baseline: 1.0549x; 1.0257x over previous
//
#include <hip/hip_runtime.h>
#include <limits.h>
#include <stdint.h>

#define ALPHA 0.2f
#define HALFA 0.1f
static constexpr int N = 8192;
static constexpr int D = 128;
static constexpr int C = 512;
static constexpr int BT = 128;          // block tile (i and j)
static constexpr int KC = 32;           // k-chunk in fp16 elems (R4-proven)
static constexpr int SL = 40;           // LDS row stride in fp16 (32 + 8 pad, R4-proven)
static constexpr int NB = N / BT;       // 64
static constexpr int NTRI = NB * (NB + 1) / 2;   // 2080 triangle blocks
static constexpr int MAXG = 64;         // e-list capacity (Poisson(16); >8 sigma)
static constexpr int ABIAS = 0x40000000; // anchor encode: raw = ABIAS - idx (raw>0 <=> present)

using half8   = __attribute__((ext_vector_type(8))) _Float16;
using floatx16 = __attribute__((ext_vector_type(16))) float;

__device__ __forceinline__ floatx16 zerov() { floatx16 v = {0.f}; return v; }

__device__ __forceinline__ half8 cvt8(const float* src) {
    float4 v0 = *(const float4*)src;
    float4 v1 = *(const float4*)(src + 4);
    half8 h;
    h[0] = (_Float16)v0.x; h[1] = (_Float16)v0.y; h[2] = (_Float16)v0.z; h[3] = (_Float16)v0.w;
    h[4] = (_Float16)v1.x; h[5] = (_Float16)v1.y; h[6] = (_Float16)v1.z; h[7] = (_Float16)v1.w;
    return h;
}

// ---------------- front: self-sufficient anchor-Gram -> T, ap, sq, xh, anchor ----------------

__launch_bounds__(256)
__global__ void k_front(const float* __restrict__ x, const int* __restrict__ labels,
                        _Float16* __restrict__ xh, float* __restrict__ sqg,
                        int* __restrict__ anchorg, float* __restrict__ T,
                        float* __restrict__ ap, float* __restrict__ out) {
    __shared__ __align__(16) _Float16 As[BT * SL];   // anchor rows c0..
    __shared__ __align__(16) _Float16 Bs[BT * SL];   // rows j0..
    __shared__ float sSqA[BT];
    __shared__ float2 colJ[BT];    // (sq_j, lab_j bits)
    __shared__ int sA[BT];         // anchor idx (INT_MAX = absent)

    const int cb = blockIdx.x, jb = blockIdx.y;
    const int c0 = cb * BT;
    const int j0 = jb * BT;
    const int tid = threadIdx.x;
    const int lane = tid & 63, w = tid >> 6;
    const int wr = w >> 1, wc = w & 1;
    const int m = lane & 31, q = lane >> 5;

    if (tid < BT) sA[tid] = INT_MAX;
    __syncthreads();

    // scan labels -> anchors for c-range (LDS atomicMin)
    const int4* lab4 = (const int4*)labels;
    for (int t = tid; t < N / 4; t += 256) {
        int4 lv = lab4[t];
        int base = t * 4;
#pragma unroll
        for (int k = 0; k < 4; ++k) {
            int l = (k == 0) ? lv.x : (k == 1) ? lv.y : (k == 2) ? lv.z : lv.w;
            int li = l - c0;
            if ((unsigned)li < (unsigned)BT) atomicMin(&sA[li], base + k);
        }
    }
    __syncthreads();

    // in-block sq: threads 0..127 -> anchor rows, 128..255 -> j rows
    {
        int r = tid & 127;
        bool isA = tid < BT;
        int row = isA ? sA[r] : (j0 + r);
        float s = 0.f;
        if (row != INT_MAX) {
            const float4* px = (const float4*)(x + (size_t)row * D);
#pragma unroll
            for (int u = 0; u < 32; ++u) {
                float4 v = px[u];
                s += v.x * v.x + v.y * v.y + v.z * v.z + v.w * v.w;
            }
        }
        if (isA) sSqA[r] = s;
        else {
            colJ[r] = make_float2(s, __int_as_float(labels[j0 + r]));
            if (cb == 0) sqg[j0 + r] = s;
        }
    }
    if (jb == 0 && tid < BT)
        anchorg[c0 + tid] = (sA[tid] == INT_MAX) ? -1 : (ABIAS - sA[tid]);
    if (cb == 0) {
        // convert this block's j rows to fp16 global (each row once across grid)
#pragma unroll
        for (int it = 0; it < 8; ++it) {
            int f = tid + it * 256;
            int row = f >> 4, g = f & 15;    // 16 8-elem units per row
            const float* src = x + (size_t)(j0 + row) * D + g * 8;
            *(half8*)(xh + (size_t)(j0 + row) * D + g * 8) = cvt8(src);
        }
    }
    if (cb == 0 && jb == 0 && tid == 0) out[0] = 0.f;

    floatx16 acc[2][2];
    acc[0][0] = zerov(); acc[0][1] = zerov(); acc[1][0] = zerov(); acc[1][1] = zerov();

    const _Float16* Abase = &As[(wr * 64 + m) * SL + q * 8];
    const _Float16* Bbase = &Bs[(wc * 64 + m) * SL + q * 8];

    for (int kc = 0; kc < D; kc += KC) {
        __syncthreads();
#pragma unroll
        for (int it = 0; it < 2; ++it) {
            int f = tid + it * 256;
            int row = f >> 2, g = f & 3;
            size_t go = (size_t)kc + g * 8;
            int ar = sA[row]; if (ar == INT_MAX) ar = 0;   // dummy, never read downstream
            *(half8*)(&As[row * SL + g * 8]) = cvt8(x + (size_t)ar * D + go);
            *(half8*)(&Bs[row * SL + g * 8]) = cvt8(x + (size_t)(j0 + row) * D + go);
        }
        __syncthreads();
#pragma unroll
        for (int ks = 0; ks < KC; ks += 16) {
            half8 a0 = *(const half8*)(Abase + ks);
            half8 a1 = *(const half8*)(Abase + 32 * SL + ks);
            half8 b0 = *(const half8*)(Bbase + ks);
            half8 b1 = *(const half8*)(Bbase + 32 * SL + ks);
            acc[0][0] = __builtin_amdgcn_mfma_f32_32x32x16_f16(a0, b0, acc[0][0], 0, 0, 0);
            acc[0][1] = __builtin_amdgcn_mfma_f32_32x32x16_f16(a0, b1, acc[0][1], 0, 0, 0);
            acc[1][0] = __builtin_amdgcn_mfma_f32_32x32x16_f16(a1, b0, acc[1][0], 0, 0, 0);
            acc[1][1] = __builtin_amdgcn_mfma_f32_32x32x16_f16(a1, b1, acc[1][1], 0, 0, 0);
        }
    }

    float sqj[2]; int labj[2];
#pragma unroll
    for (int tn = 0; tn < 2; ++tn) {
        float2 cj = colJ[wc * 64 + tn * 32 + m];
        sqj[tn] = cj.x; labj[tn] = __float_as_int(cj.y);
    }

#pragma unroll
    for (int tm = 0; tm < 2; ++tm) {
        int rbase = wr * 64 + tm * 32 + 4 * q;
#pragma unroll
        for (int rr = 0; rr < 16; ++rr) {
            int row = rbase + (rr & 3) + 8 * (rr >> 2);
            int c = c0 + row;
            float sqa = sSqA[row];
#pragma unroll
            for (int tn = 0; tn < 2; ++tn) {
                int col = wc * 64 + tn * 32 + m;
                float Dv = fmaf(-2.f, acc[tm][tn][rr], sqa + sqj[tn]);
                T[(size_t)c * N + j0 + col] = Dv;
                if (labj[tn] == c) ap[j0 + col] = Dv;
            }
        }
    }
}

// ---------------- mega: per-label term1 blocks + term2 triangle blocks ----------------

__launch_bounds__(256)
__global__ void k_mega(const _Float16* __restrict__ xh, const int* __restrict__ labels,
                       const int* __restrict__ anchor, const float* __restrict__ sq,
                       const float* __restrict__ ap, const float* __restrict__ T,
                       float* __restrict__ out) {
    __shared__ __align__(16) _Float16 As[BT * SL];
    __shared__ __align__(16) _Float16 Bs[BT * SL];
    __shared__ float4 rowE[BT];    // (e2i, labi bits, sq_i, -)
    __shared__ float4 colE[BT];    // (e2j, labj bits, sq_j, -)
    __shared__ float wsum[4];

    const int tid = threadIdx.x;
    const int lane = tid & 63, w = tid >> 6;
    float local = 0.f;

    if ((int)blockIdx.x < C) {
        // ---- term1, label c: gather e-list by scanning labels, then stream T[c][:] once ----
        const int c = blockIdx.x;
        __shared__ float sge[MAXG];
        __shared__ int sglen;
        int raw = anchor[c];
        if (raw > 0) {
            int a = ABIAS - raw;
            if (tid == 0) sglen = 0;
            __syncthreads();
            for (int t = tid; t < N; t += 256) {
                if (labels[t] == c && t != a) {
                    int slot = atomicAdd(&sglen, 1);
                    if (slot < MAXG) sge[slot] = ap[t] + HALFA;
                }
            }
            __syncthreads();
            int glen = sglen; if (glen > MAXG) glen = MAXG;
            if (glen > 0) {
                const float4* trow = (const float4*)(T + (size_t)c * N);
                const int4* lrow = (const int4*)labels;
#pragma unroll 2
                for (int ch = 0; ch < 8; ++ch) {
                    float4 tv = trow[ch * 256 + tid];
                    int4 lv = lrow[ch * 256 + tid];
                    for (int g = 0; g < glen; ++g) {
                        float e = sge[g];
                        float u;
                        u = e - tv.x; if (lv.x != c && __builtin_fabsf(u) < HALFA) local += u + HALFA;
                        u = e - tv.y; if (lv.y != c && __builtin_fabsf(u) < HALFA) local += u + HALFA;
                        u = e - tv.z; if (lv.z != c && __builtin_fabsf(u) < HALFA) local += u + HALFA;
                        u = e - tv.w; if (lv.w != c && __builtin_fabsf(u) < HALFA) local += u + HALFA;
                    }
                }
            }
        }
    } else {
        // ---- term2: symmetric Gram triangle, register-only epilogue ----
        int rem = blockIdx.x - C, br = 0;
        while (rem >= NB - br) { rem -= NB - br; ++br; }
        const int bc = br + rem;
        const int i0 = br * BT;
        const int j0 = bc * BT;
        const bool diag = (br == bc);
        const int wr = w >> 1, wc = w & 1;
        const int m = lane & 31, q = lane >> 5;

        if (tid < BT) {
            int i = i0 + tid;
            int li = labels[i];
            int a = ABIAS - anchor[li];
            float sqi = sq[i];
            float e2 = (i == a) ? -1e30f : ap[i] + HALFA - sqi;
            rowE[tid] = make_float4(e2, __int_as_float(li), sqi, 0.f);
        } else {
            int t = tid - BT;
            int j = j0 + t;
            int lj = labels[j];
            int a = ABIAS - anchor[lj];
            float sqj = sq[j];
            float e2 = (j == a) ? -1e30f : ap[j] + HALFA - sqj;
            colE[t] = make_float4(e2, __int_as_float(lj), sqj, 0.f);
        }

        floatx16 acc[2][2];
        acc[0][0] = zerov(); acc[0][1] = zerov(); acc[1][0] = zerov(); acc[1][1] = zerov();

        const _Float16* Abase = &As[(wr * 64 + m) * SL + q * 8];
        const _Float16* Bbase = &Bs[(wc * 64 + m) * SL + q * 8];

        for (int kc = 0; kc < D; kc += KC) {
            __syncthreads();
#pragma unroll
            for (int it = 0; it < 2; ++it) {
                int f = tid + it * 256;
                int row = f >> 2, g = f & 3;
                size_t go = (size_t)kc + g * 8;
                half8 v = *(const half8*)(xh + (size_t)(i0 + row) * D + go);
                *(half8*)(&As[row * SL + g * 8]) = v;
                half8 u = *(const half8*)(xh + (size_t)(j0 + row) * D + go);
                *(half8*)(&Bs[row * SL + g * 8]) = u;
            }
            __syncthreads();
#pragma unroll
            for (int ks = 0; ks < KC; ks += 16) {
                half8 a0 = *(const half8*)(Abase + ks);
                half8 a1 = *(const half8*)(Abase + 32 * SL + ks);
                half8 b0 = *(const half8*)(Bbase + ks);
                half8 b1 = *(const half8*)(Bbase + 32 * SL + ks);
                acc[0][0] = __builtin_amdgcn_mfma_f32_32x32x16_f16(a0, b0, acc[0][0], 0, 0, 0);
                acc[0][1] = __builtin_amdgcn_mfma_f32_32x32x16_f16(a0, b1, acc[0][1], 0, 0, 0);
                acc[1][0] = __builtin_amdgcn_mfma_f32_32x32x16_f16(a1, b0, acc[1][0], 0, 0, 0);
                acc[1][1] = __builtin_amdgcn_mfma_f32_32x32x16_f16(a1, b1, acc[1][1], 0, 0, 0);
            }
        }

        float sqj[2], e2j[2]; int labj[2];
#pragma unroll
        for (int tn = 0; tn < 2; ++tn) {
            float4 cj = colE[wc * 64 + tn * 32 + m];
            e2j[tn] = cj.x; labj[tn] = __float_as_int(cj.y); sqj[tn] = cj.z;
        }

        // ori1 (i pos): u2 = 2*dot + e2i - sq_j ; ori2 (j pos): u2b = 2*dot + e2j - sq_i
#pragma unroll
        for (int tm = 0; tm < 2; ++tm) {
            int rbase = wr * 64 + tm * 32 + 4 * q;
#pragma unroll
            for (int rr = 0; rr < 16; ++rr) {
                int row = rbase + (rr & 3) + 8 * (rr >> 2);
                float4 re = rowE[row];
                float e2i = re.x, sqi = re.z;
                int labi = __float_as_int(re.y);
#pragma unroll
                for (int tn = 0; tn < 2; ++tn) {
                    if (labi != labj[tn]) {
                        float dot = acc[tm][tn][rr];
                        float u2 = fmaf(2.f, dot, e2i - sqj[tn]);
                        if (__builtin_fabsf(u2) < HALFA) local += u2 + HALFA;
                        if (!diag) {
                            float u2b = fmaf(2.f, dot, e2j[tn] - sqi);
                            if (__builtin_fabsf(u2b) < HALFA) local += u2b + HALFA;
                        }
                    }
                }
            }
        }
    }

    // block reduce -> one fire-and-forget float atomic
#pragma unroll
    for (int off = 32; off; off >>= 1) local += __shfl_down(local, off);
    if (lane == 0) wsum[w] = local;
    __syncthreads();
    if (tid == 0) atomicAdd(out, wsum[0] + wsum[1] + wsum[2] + wsum[3]);
}

// ---------------- launch ----------------

extern "C" void kernel_launch(void* const* d_in, const int* in_sizes, int n_in,
                              void* d_out, int out_size, void* d_ws, size_t ws_size,
                              hipStream_t stream) {
    const float* x = (const float*)d_in[0];
    const int* labels = (const int*)d_in[1];
    float* out = (float*)d_out;

    char* p = (char*)d_ws;
    int* anchor = (int*)p;            p += C * 4;
    float* sq = (float*)p;            p += N * 4;
    float* ap = (float*)p;            p += N * 4;
    p = (char*)(((uintptr_t)p + 255) & ~(uintptr_t)255);
    float* T = (float*)p;             p += (size_t)C * N * 4;   // 16 MB
    _Float16* xh = (_Float16*)p;      // N*D*2 = 2 MB

    dim3 gf(C / BT, N / BT);
    k_front<<<gf, 256, 0, stream>>>(x, labels, xh, sq, anchor, T, ap, out);
    k_mega<<<C + NTRI, 256, 0, stream>>>(xh, labels, anchor, sq, ap, T, out);
}